// Round 6
// baseline (77.393 us; speedup 1.0000x reference)
//
#include <hip/hip_runtime.h>
#include <hip/hip_bf16.h>

typedef __attribute__((ext_vector_type(8))) short short8;
typedef __attribute__((ext_vector_type(4))) float f32x4;

// Manual fp32 -> bf16 bits, round-to-nearest-even (finite values only).
__device__ __forceinline__ unsigned short bf16_bits(float f) {
  unsigned int u = __float_as_uint(f);
  return (unsigned short)((u + 0x7FFFu + ((u >> 16) & 1u)) >> 16);
}

// Packed pair fp32 -> 2x bf16 (RTNE), as one uint (v_cvt_pk_bf16_f32).
__device__ __forceinline__ unsigned int pack_bf16(float a, float b) {
  float2 t; t.x = a; t.y = b;
  __hip_bfloat162 h = __float22bfloat162_rn(t);
  return *reinterpret_cast<unsigned int*>(&h);
}

// Rotate-reduce step over each 16-lane DPP row: p += ror(p, n). CTRL must be
// an immediate -> template parameter. After n = 1,2,4,8 every lane of the
// 16-lane group holds the group sum.
template <int CTRL>
__device__ __forceinline__ float dpp_ror_add(float p) {
  int s = __builtin_amdgcn_update_dpp(0, __float_as_int(p), CTRL, 0xF, 0xF, true);
  return p + __int_as_float(s);
}

// ---------------------------------------------------------------------------
// Precompute: hx[512][256] = x @ W1[:128]          (fp32)
//             hy[512][256] = y @ W1[128:] + b1     (fp32)
//             W2T[n][k]    = bf16(W2[k][n])        (bf16 bits as ushort)
// ---------------------------------------------------------------------------
__global__ void k_pre(const float* __restrict__ x, const float* __restrict__ y,
                      const float* __restrict__ W1, const float* __restrict__ b1,
                      const float* __restrict__ W2,
                      float* __restrict__ hx, float* __restrict__ hy,
                      unsigned short* __restrict__ W2T) {
  const int b = blockIdx.x;
  const int t = threadIdx.x;
  if (b < 128) {
    const bool isx = (b < 64);
    const int i0 = (isx ? b : (b - 64)) * 8;
    const float* __restrict__ src = isx ? x : y;
    const float* __restrict__ W = W1 + (isx ? 0 : 128 * 256);
    float acc[8];
    const float binit = isx ? 0.0f : b1[t];
#pragma unroll
    for (int r = 0; r < 8; ++r) acc[r] = binit;
#pragma unroll 4
    for (int d = 0; d < 128; ++d) {
      const float wv = W[d * 256 + t];  // coalesced across t
#pragma unroll
      for (int r = 0; r < 8; ++r) acc[r] += src[(i0 + r) * 128 + d] * wv;  // uniform loads
    }
    float* __restrict__ dst = isx ? hx : hy;
#pragma unroll
    for (int r = 0; r < 8; ++r) dst[(i0 + r) * 256 + t] = acc[r];
  } else {
    const int n = b - 128;
    W2T[n * 256 + t] = bf16_bits(W2[t * 256 + n]);
  }
}

// ---------------------------------------------------------------------------
// Main fused kernel, v5 (software-pipelined).
// Block = 256 threads (4 waves), grid = 512 (ig 0..63 x j-tile 0..7).
// TWO blocks/CU, anti-phased. Wave w: all 64 rows (mf=4), cols w*64.. (nf=4).
// bq[8][4] short8 = 128 VGPR persistent B.
// Per g, ONE barrier:
//   store(g-1) | issue A-gen chunk loads early, pack+write mid-K-loop
//   (double-buffered A_lds) | K-loop 8kk x (4 ds_read_b128 + 16 MFMA,
//   setprio) | epilogue relu(acc+b2).W3 reduced via DPP row_ror (VALU pipe,
//   no LDS shuffles, no extra barrier) -> red[g&1] | __syncthreads().
// MFMA v_mfma_f32_16x16x32_bf16 frag layout (verified R1):
//   A: row=l15, k=8*l4+e ; B: col=l15, k=8*l4+e ; C: col=l15, row=4*l4+reg
// ---------------------------------------------------------------------------
__launch_bounds__(256, 2)
__global__ void k_main(const float* __restrict__ hx, const float* __restrict__ hy,
                       const unsigned short* __restrict__ W2T,
                       const float* __restrict__ b2, const float* __restrict__ W3,
                       const float* __restrict__ b3, float* __restrict__ out) {
  __shared__ unsigned short A_lds[2][64 * 264];  // 2 x 33792 B, row pad +8
  __shared__ float red[2][4 * 68];               // 2 x 1088 B

  const int tid = threadIdx.x;
  const int lane = tid & 63;
  const int w = tid >> 6;        // wave 0..3 -> col slice w*64
  const int l15 = lane & 15;
  const int l4 = lane >> 4;
  const int ig = blockIdx.x >> 3;
  const int j0 = (blockIdx.x & 7) * 64;
  const int i0 = ig * 8;

  // ---- persistent B fragments: col = w*64+nf*16+l15, k = kk*32+l4*8 ----
  short8 bq[8][4];
  {
    const unsigned short* bb = W2T + (w * 64 + l15) * 256 + l4 * 8;
#pragma unroll
    for (int nf = 0; nf < 4; ++nf)
#pragma unroll
      for (int kk = 0; kk < 8; ++kk)
        bq[kk][nf] = *reinterpret_cast<const short8*>(bb + nf * 16 * 256 + kk * 32);
  }

  // ---- epilogue constants ----
  float b2v[4], w3v[4];
#pragma unroll
  for (int nf = 0; nf < 4; ++nf) {
    b2v[nf] = b2[w * 64 + nf * 16 + l15];
    w3v[nf] = W3[w * 64 + nf * 16 + l15];
  }
  const float b3v = b3[0];

  // ---- A-gen for g = 0 into buffer 0 (not pipelined; once) ----
  {
    const float4 xv = *reinterpret_cast<const float4*>(&hx[i0 * 256 + lane * 4]);
#pragma unroll
    for (int r = 0; r < 16; ++r) {
      const float4 hv = *reinterpret_cast<const float4*>(&hy[(j0 + w * 16 + r) * 256 + lane * 4]);
      uint2 pk;
      pk.x = pack_bf16(fmaxf(hv.x + xv.x, 0.f), fmaxf(hv.y + xv.y, 0.f));
      pk.y = pack_bf16(fmaxf(hv.z + xv.z, 0.f), fmaxf(hv.w + xv.w, 0.f));
      *reinterpret_cast<uint2*>(&A_lds[0][(w * 16 + r) * 264 + lane * 4]) = pk;
    }
  }
  __syncthreads();

#pragma unroll 1
  for (int g = 0; g < 8; ++g) {
    const int buf = g & 1;
    const bool pre = (g < 7);

    // ---- store results of g-1 (red written pre-barrier last iter) ----
    if (g > 0 && tid < 64) {
      const float* rb = red[1 - buf];
      const float s = rb[0 * 68 + tid] + rb[1 * 68 + tid] +
                      rb[2 * 68 + tid] + rb[3 * 68 + tid] + b3v;
      out[(i0 + g - 1) * 512 + j0 + tid] = s;
    }

    // ---- issue xv + chunk0 loads for A(g+1) ----
    float4 xv, hv0, hv1, hv2, hv3;
    const float* __restrict__ hyb = &hy[(j0 + w * 16) * 256 + lane * 4];
    if (pre) {
      xv = *reinterpret_cast<const float4*>(&hx[(i0 + g + 1) * 256 + lane * 4]);
      hv0 = *reinterpret_cast<const float4*>(hyb + 0 * 256);
      hv1 = *reinterpret_cast<const float4*>(hyb + 1 * 256);
      hv2 = *reinterpret_cast<const float4*>(hyb + 2 * 256);
      hv3 = *reinterpret_cast<const float4*>(hyb + 3 * 256);
    }

    f32x4 acc[4][4];
#pragma unroll
    for (int mf = 0; mf < 4; ++mf)
#pragma unroll
      for (int nf = 0; nf < 4; ++nf) acc[mf][nf] = (f32x4){0.f, 0.f, 0.f, 0.f};

    unsigned short* __restrict__ Aw = &A_lds[1 - buf][(w * 16) * 264 + lane * 4];
    const unsigned short* __restrict__ Ar = &A_lds[buf][0];

    // helper macro: one kk step (4 ds_read_b128 + 16 MFMA)
#define KK_STEP(kk)                                                            \
    {                                                                          \
      short8 af[4];                                                            \
      _Pragma("unroll")                                                        \
      for (int mf = 0; mf < 4; ++mf)                                           \
        af[mf] = *reinterpret_cast<const short8*>(                             \
            &Ar[(mf * 16 + l15) * 264 + (kk) * 32 + l4 * 8]);                  \
      __builtin_amdgcn_s_setprio(1);                                           \
      _Pragma("unroll")                                                        \
      for (int mf = 0; mf < 4; ++mf)                                           \
        _Pragma("unroll")                                                      \
        for (int nf = 0; nf < 4; ++nf)                                         \
          acc[mf][nf] = __builtin_amdgcn_mfma_f32_16x16x32_bf16(               \
              af[mf], bq[kk][nf], acc[mf][nf], 0, 0, 0);                       \
      __builtin_amdgcn_s_setprio(0);                                           \
    }

    // chunk consume: pack 4 rows into A[1-buf], issue next chunk's loads
#define CHUNK_FLUSH(c)                                                         \
    if (pre) {                                                                 \
      uint2 pk;                                                                \
      pk.x = pack_bf16(fmaxf(hv0.x + xv.x, 0.f), fmaxf(hv0.y + xv.y, 0.f));    \
      pk.y = pack_bf16(fmaxf(hv0.z + xv.z, 0.f), fmaxf(hv0.w + xv.w, 0.f));    \
      *reinterpret_cast<uint2*>(&Aw[((c) * 4 + 0) * 264]) = pk;                \
      pk.x = pack_bf16(fmaxf(hv1.x + xv.x, 0.f), fmaxf(hv1.y + xv.y, 0.f));    \
      pk.y = pack_bf16(fmaxf(hv1.z + xv.z, 0.f), fmaxf(hv1.w + xv.w, 0.f));    \
      *reinterpret_cast<uint2*>(&Aw[((c) * 4 + 1) * 264]) = pk;                \
      pk.x = pack_bf16(fmaxf(hv2.x + xv.x, 0.f), fmaxf(hv2.y + xv.y, 0.f));    \
      pk.y = pack_bf16(fmaxf(hv2.z + xv.z, 0.f), fmaxf(hv2.w + xv.w, 0.f));    \
      *reinterpret_cast<uint2*>(&Aw[((c) * 4 + 2) * 264]) = pk;                \
      pk.x = pack_bf16(fmaxf(hv3.x + xv.x, 0.f), fmaxf(hv3.y + xv.y, 0.f));    \
      pk.y = pack_bf16(fmaxf(hv3.z + xv.z, 0.f), fmaxf(hv3.w + xv.w, 0.f));    \
      *reinterpret_cast<uint2*>(&Aw[((c) * 4 + 3) * 264]) = pk;                \
      if ((c) < 3) {                                                           \
        hv0 = *reinterpret_cast<const float4*>(hyb + ((c) * 4 + 4) * 256);     \
        hv1 = *reinterpret_cast<const float4*>(hyb + ((c) * 4 + 5) * 256);     \
        hv2 = *reinterpret_cast<const float4*>(hyb + ((c) * 4 + 6) * 256);     \
        hv3 = *reinterpret_cast<const float4*>(hyb + ((c) * 4 + 7) * 256);     \
      }                                                                        \
    }

    KK_STEP(0)
    KK_STEP(1)
    CHUNK_FLUSH(0)
    KK_STEP(2)
    KK_STEP(3)
    CHUNK_FLUSH(1)
    KK_STEP(4)
    KK_STEP(5)
    CHUNK_FLUSH(2)
    KK_STEP(6)
    KK_STEP(7)
    CHUNK_FLUSH(3)
#undef KK_STEP
#undef CHUNK_FLUSH

    // ---- epilogue: p = relu(acc+b2).w3 over nf; DPP ror-reduce over l15 ----
    float pr[4][4];
#pragma unroll
    for (int mf = 0; mf < 4; ++mf) {
#pragma unroll
      for (int reg = 0; reg < 4; ++reg) {
        float p = 0.f;
#pragma unroll
        for (int nf = 0; nf < 4; ++nf)
          p += fmaxf(acc[mf][nf][reg] + b2v[nf], 0.f) * w3v[nf];
        p = dpp_ror_add<0x121>(p);  // ror 1
        p = dpp_ror_add<0x122>(p);  // ror 2
        p = dpp_ror_add<0x124>(p);  // ror 4
        p = dpp_ror_add<0x128>(p);  // ror 8
        pr[mf][reg] = p;            // sum over 16 cols-of-group, all lanes
      }
    }
    // lane (l4, l15) writes partial (mf = l15>>2, reg = l15&3):
    // row = mf*16 + l4*4 + reg, addr = w*68 + row -> banks 2-way max.
    {
      float* rb = red[buf];
#pragma unroll
      for (int mf = 0; mf < 4; ++mf)
#pragma unroll
        for (int reg = 0; reg < 4; ++reg)
          if (l15 == mf * 4 + reg)
            rb[w * 68 + mf * 16 + l4 * 4 + reg] = pr[mf][reg];
    }

    __syncthreads();  // A(g+1) ready, red(g) ready, A(g) reads done
  }

  // ---- store for g = 7 ----
  if (tid < 64) {
    const float* rb = red[1];
    const float s = rb[0 * 68 + tid] + rb[1 * 68 + tid] +
                    rb[2 * 68 + tid] + rb[3 * 68 + tid] + b3v;
    out[(i0 + 7) * 512 + j0 + tid] = s;
  }
}

extern "C" void kernel_launch(void* const* d_in, const int* in_sizes, int n_in,
                              void* d_out, int out_size, void* d_ws, size_t ws_size,
                              hipStream_t stream) {
  const float* x  = (const float*)d_in[0];
  const float* y  = (const float*)d_in[1];
  const float* W1 = (const float*)d_in[2];
  const float* b1 = (const float*)d_in[3];
  const float* W2 = (const float*)d_in[4];
  const float* b2 = (const float*)d_in[5];
  const float* W3 = (const float*)d_in[6];
  const float* b3 = (const float*)d_in[7];
  float* out = (float*)d_out;

  char* ws = (char*)d_ws;
  float* hx = (float*)ws;                                   // 524288 B
  float* hy = (float*)(ws + 524288);                        // 524288 B
  unsigned short* W2T = (unsigned short*)(ws + 1048576);    // 131072 B

  k_pre<<<384, 256, 0, stream>>>(x, y, W1, b1, W2, hx, hy, W2T);
  k_main<<<512, 256, 0, stream>>>(hx, hy, W2T, b2, W3, b3, out);
}

// Round 7
// 68.973 us; speedup vs baseline: 1.1221x; 1.1221x over previous
//
#include <hip/hip_runtime.h>
#include <hip/hip_fp16.h>

typedef __attribute__((ext_vector_type(8))) _Float16 half8;
typedef __attribute__((ext_vector_type(4))) float f32x4;

// DPP rotate-reduce within each 16-lane row: after ror 1,2,4,8 all 16 lanes
// hold the group sum. Validated numerically in R6.
template <int CTRL>
__device__ __forceinline__ float dpp_ror_add(float p) {
  int s = __builtin_amdgcn_update_dpp(0, __float_as_int(p), CTRL, 0xF, 0xF, true);
  return p + __int_as_float(s);
}

__device__ __forceinline__ unsigned int pack_f16x2(float a, float b) {
  __half2 h = __floats2half2_rn(a, b);  // .x (low) = a
  return *reinterpret_cast<unsigned int*>(&h);
}

__device__ __forceinline__ half8 relu8(half8 s) {
  const _Float16 z = (_Float16)0.f;
#pragma unroll
  for (int e = 0; e < 8; ++e) s[e] = s[e] > z ? s[e] : z;
  return s;
}

// ---------------------------------------------------------------------------
// Precompute (fp32 math, f16 outputs):
//   hx2[512][128] uint = f16 pairs of x @ W1[:128]
//   hy2[512][128] uint = f16 pairs of y @ W1[128:] + b1
//   W2T2[n][128]  uint = f16 pairs of W2[k][n] (transposed)
//   out[512*512]  = b3  (k_main atomicAdds partials on top)
// grid 512 x 256 thr: b<64 hx | b<128 hy | b<384 W2T | b<512 out-init
// ---------------------------------------------------------------------------
__global__ void k_pre(const float* __restrict__ x, const float* __restrict__ y,
                      const float* __restrict__ W1, const float* __restrict__ b1,
                      const float* __restrict__ W2, const float* __restrict__ b3,
                      unsigned int* __restrict__ hx2, unsigned int* __restrict__ hy2,
                      unsigned int* __restrict__ W2T2, float* __restrict__ out) {
  const int b = blockIdx.x;
  const int t = threadIdx.x;
  if (b < 128) {
    const bool isx = (b < 64);
    const int i0 = (isx ? b : (b - 64)) * 8;
    const float* __restrict__ src = isx ? x : y;
    const float* __restrict__ W = W1 + (isx ? 0 : 128 * 256);
    float acc[8];
    const float binit = isx ? 0.0f : b1[t];
#pragma unroll
    for (int r = 0; r < 8; ++r) acc[r] = binit;
#pragma unroll 4
    for (int d = 0; d < 128; ++d) {
      const float wv = W[d * 256 + t];  // coalesced across t
#pragma unroll
      for (int r = 0; r < 8; ++r) acc[r] += src[(i0 + r) * 128 + d] * wv;  // uniform loads
    }
    unsigned int* __restrict__ dst = isx ? hx2 : hy2;
#pragma unroll
    for (int r = 0; r < 8; ++r) {
      const float o = __shfl_xor(acc[r], 1, 64);
      if (!(t & 1)) dst[(i0 + r) * 128 + (t >> 1)] = pack_f16x2(acc[r], o);
    }
  } else if (b < 384) {
    const int n = b - 128;
    const float wv = W2[t * 256 + n];
    const float o = __shfl_xor(wv, 1, 64);
    if (!(t & 1)) W2T2[n * 128 + (t >> 1)] = pack_f16x2(wv, o);
  } else {
    const float bv = b3[0];
    const int base = (b - 384) * 2048 + t * 8;
    const float4 v = {bv, bv, bv, bv};
    *reinterpret_cast<float4*>(out + base) = v;
    *reinterpret_cast<float4*>(out + base + 4) = v;
  }
}

// ---------------------------------------------------------------------------
// Main fused kernel, v7 (f16 + 1-barrier + atomic epilogue).
// Block = 256 thr (4 waves), grid = 512 (ig 0..63 x j-tile 0..7), 2 blocks/CU.
// Wave w: all 64 rows (mf=4), cols w*64..+63 (nf=4).
//   bq[8][4] half8 = 128 VGPR persistent W2T2 slice.
// Per g (ONE barrier, A_lds double-buffered):
//   issue xv + hy chunk1 (4 b128, 2 rows each) |
//   K-loop: 8 kk x (4 ds_read_b128 + 16 MFMA f16, setprio) |
//   epilogue: p[mf][reg] = sum_nf relu(acc+b2)*w3; issue hy chunk2;
//             DPP ror-reduce (16 lanes) -> select tree -> 1 atomicAdd
//             (64 rows, out pre-init'd to b3) |
//   A-pack(g+1): pk_add_f16 + pk_max + 8 ds_write_b128 into buf^1 |
//   __syncthreads().
// MFMA f16 frag layout (shape-determined, same as bf16, verified R1):
//   A: row=l15, k=8*l4+e ; B: col=l15, k=8*l4+e ; C: col=l15, row=4*l4+reg
// ---------------------------------------------------------------------------
__launch_bounds__(256, 2)
__global__ void k_main(const unsigned int* __restrict__ hx2,
                       const unsigned int* __restrict__ hy2,
                       const unsigned int* __restrict__ W2T2,
                       const float* __restrict__ b2, const float* __restrict__ W3,
                       float* __restrict__ out) {
  __shared__ __attribute__((aligned(16))) _Float16 A_lds[2][64 * 264];  // 2x33792B

  const int tid = threadIdx.x;
  const int lane = tid & 63;
  const int w = tid >> 6;        // wave 0..3 -> col slice w*64
  const int l15 = lane & 15;
  const int l4 = lane >> 4;
  const int ig = blockIdx.x >> 3;
  const int j0 = (blockIdx.x & 7) * 64;
  const int i0 = ig * 8;

  // ---- persistent B fragments: col = w*64+nf*16+l15, k = kk*32+l4*8 ----
  half8 bq[8][4];
  {
    const unsigned int* bb = W2T2 + (w * 64 + l15) * 128 + l4 * 4;
#pragma unroll
    for (int nf = 0; nf < 4; ++nf)
#pragma unroll
      for (int kk = 0; kk < 8; ++kk)
        bq[kk][nf] = *reinterpret_cast<const half8*>(bb + nf * 16 * 128 + kk * 16);
  }

  // ---- epilogue constants ----
  float b2v[4], w3v[4];
#pragma unroll
  for (int nf = 0; nf < 4; ++nf) {
    b2v[nf] = b2[w * 64 + nf * 16 + l15];
    w3v[nf] = W3[w * 64 + nf * 16 + l15];
  }
  const int orow = (l15 >> 2) * 16 + l4 * 4 + (l15 & 3);
  float* const outp = out + j0 + orow;

  // ---- A-gen lane geometry: each b128 covers 2 rows (64 lanes x 8 f16) ----
  const int lrow = lane >> 5;          // 0/1: which of the 2 rows
  const int lk4 = (lane & 31) * 4;     // uint offset within row (8 f16)
  const unsigned int* __restrict__ hyb = hy2 + (j0 + w * 16 + lrow) * 128 + lk4;
  const int arow0 = w * 16 + lrow;     // A row for chunk c: arow0 + 2c
  const int aoff = (lane & 31) * 8;    // f16 offset within A row

  // ---- prologue: A-gen for g=0 into buffer 0 ----
  {
    const half8 xv = *reinterpret_cast<const half8*>(hx2 + i0 * 128 + lk4);
    half8 hv[8];
#pragma unroll
    for (int c = 0; c < 8; ++c)
      hv[c] = *reinterpret_cast<const half8*>(hyb + c * 256);
#pragma unroll
    for (int c = 0; c < 8; ++c) {
      half8 s = relu8(hv[c] + xv);
      *reinterpret_cast<half8*>(&A_lds[0][(arow0 + 2 * c) * 264 + aoff]) = s;
    }
  }
  __syncthreads();

#pragma unroll 1
  for (int g = 0; g < 8; ++g) {
    const int buf = g & 1;
    const bool pre = (g < 7);

    // ---- issue xv + hy chunk1 for A(g+1): latency hides under K-loop ----
    half8 xv, hva0, hva1, hva2, hva3;
    if (pre) {
      xv = *reinterpret_cast<const half8*>(hx2 + (i0 + g + 1) * 128 + lk4);
      hva0 = *reinterpret_cast<const half8*>(hyb + 0 * 256);
      hva1 = *reinterpret_cast<const half8*>(hyb + 1 * 256);
      hva2 = *reinterpret_cast<const half8*>(hyb + 2 * 256);
      hva3 = *reinterpret_cast<const half8*>(hyb + 3 * 256);
    }

    f32x4 acc[4][4];
#pragma unroll
    for (int mf = 0; mf < 4; ++mf)
#pragma unroll
      for (int nf = 0; nf < 4; ++nf) acc[mf][nf] = (f32x4){0.f, 0.f, 0.f, 0.f};

    const _Float16* __restrict__ Ar = &A_lds[buf][0];
#pragma unroll
    for (int kk = 0; kk < 8; ++kk) {
      half8 af[4];
#pragma unroll
      for (int mf = 0; mf < 4; ++mf)
        af[mf] = *reinterpret_cast<const half8*>(
            &Ar[(mf * 16 + l15) * 264 + kk * 32 + l4 * 8]);
      __builtin_amdgcn_s_setprio(1);
#pragma unroll
      for (int mf = 0; mf < 4; ++mf)
#pragma unroll
        for (int nf = 0; nf < 4; ++nf)
          acc[mf][nf] = __builtin_amdgcn_mfma_f32_16x16x32_f16(
              af[mf], bq[kk][nf], acc[mf][nf], 0, 0, 0);
      __builtin_amdgcn_s_setprio(0);
    }

    // ---- epilogue: p[mf][reg] = sum_nf relu(acc+b2)*w3 (retires acc) ----
    float pr[4][4];
#pragma unroll
    for (int mf = 0; mf < 4; ++mf)
#pragma unroll
      for (int reg = 0; reg < 4; ++reg) {
        float p = 0.f;
#pragma unroll
        for (int nf = 0; nf < 4; ++nf)
          p += fmaxf(acc[mf][nf][reg] + b2v[nf], 0.f) * w3v[nf];
        pr[mf][reg] = p;
      }

    // ---- issue hy chunk2 (latency hides under DPP/select below) ----
    half8 hvb0, hvb1, hvb2, hvb3;
    if (pre) {
      hvb0 = *reinterpret_cast<const half8*>(hyb + 4 * 256);
      hvb1 = *reinterpret_cast<const half8*>(hyb + 5 * 256);
      hvb2 = *reinterpret_cast<const half8*>(hyb + 6 * 256);
      hvb3 = *reinterpret_cast<const half8*>(hyb + 7 * 256);
    }

    // ---- DPP 16-lane reduce (all lanes get group sums) ----
#pragma unroll
    for (int mf = 0; mf < 4; ++mf)
#pragma unroll
      for (int reg = 0; reg < 4; ++reg) {
        float p = pr[mf][reg];
        p = dpp_ror_add<0x121>(p);
        p = dpp_ror_add<0x122>(p);
        p = dpp_ror_add<0x124>(p);
        p = dpp_ror_add<0x128>(p);
        pr[mf][reg] = p;
      }
    // ---- select tree: lane (l4,l15) takes pr[l15>>2][l15&3] (static idx) ----
    {
      const bool s0 = (l15 & 1), s1 = (l15 & 2), s2 = (l15 & 4), s3 = (l15 & 8);
      const float a0 = s0 ? pr[0][1] : pr[0][0];
      const float a1 = s0 ? pr[0][3] : pr[0][2];
      const float a2 = s0 ? pr[1][1] : pr[1][0];
      const float a3 = s0 ? pr[1][3] : pr[1][2];
      const float a4 = s0 ? pr[2][1] : pr[2][0];
      const float a5 = s0 ? pr[2][3] : pr[2][2];
      const float a6 = s0 ? pr[3][1] : pr[3][0];
      const float a7 = s0 ? pr[3][3] : pr[3][2];
      const float c0 = s1 ? a1 : a0;
      const float c1 = s1 ? a3 : a2;
      const float c2 = s1 ? a5 : a4;
      const float c3 = s1 ? a7 : a6;
      const float d0 = s2 ? c1 : c0;
      const float d1 = s2 ? c3 : c2;
      const float v = s3 ? d1 : d0;
      atomicAdd(outp + (i0 + g) * 512, v);  // row orow of out[i0+g][j0..]
    }

    // ---- A-pack(g+1) into buf^1 (pk_add_f16 + relu + b128 writes) ----
    if (pre) {
      _Float16* __restrict__ Awb = &A_lds[1 - buf][0];
      half8 s;
      s = relu8(hva0 + xv);
      *reinterpret_cast<half8*>(&Awb[(arow0 + 0) * 264 + aoff]) = s;
      s = relu8(hva1 + xv);
      *reinterpret_cast<half8*>(&Awb[(arow0 + 2) * 264 + aoff]) = s;
      s = relu8(hva2 + xv);
      *reinterpret_cast<half8*>(&Awb[(arow0 + 4) * 264 + aoff]) = s;
      s = relu8(hva3 + xv);
      *reinterpret_cast<half8*>(&Awb[(arow0 + 6) * 264 + aoff]) = s;
      s = relu8(hvb0 + xv);
      *reinterpret_cast<half8*>(&Awb[(arow0 + 8) * 264 + aoff]) = s;
      s = relu8(hvb1 + xv);
      *reinterpret_cast<half8*>(&Awb[(arow0 + 10) * 264 + aoff]) = s;
      s = relu8(hvb2 + xv);
      *reinterpret_cast<half8*>(&Awb[(arow0 + 12) * 264 + aoff]) = s;
      s = relu8(hvb3 + xv);
      *reinterpret_cast<half8*>(&Awb[(arow0 + 14) * 264 + aoff]) = s;
    }
    __syncthreads();  // A(g+1) ready; buf(g) reads done
  }
}

extern "C" void kernel_launch(void* const* d_in, const int* in_sizes, int n_in,
                              void* d_out, int out_size, void* d_ws, size_t ws_size,
                              hipStream_t stream) {
  const float* x  = (const float*)d_in[0];
  const float* y  = (const float*)d_in[1];
  const float* W1 = (const float*)d_in[2];
  const float* b1 = (const float*)d_in[3];
  const float* W2 = (const float*)d_in[4];
  const float* b2 = (const float*)d_in[5];
  const float* W3 = (const float*)d_in[6];
  const float* b3 = (const float*)d_in[7];
  float* out = (float*)d_out;

  char* ws = (char*)d_ws;
  unsigned int* hx2  = (unsigned int*)ws;              // 512*128*4 = 262144 B
  unsigned int* hy2  = (unsigned int*)(ws + 262144);   // 262144 B
  unsigned int* W2T2 = (unsigned int*)(ws + 524288);   // 256*128*4 = 131072 B

  k_pre<<<512, 256, 0, stream>>>(x, y, W1, b1, W2, b3, hx2, hy2, W2T2, out);
  k_main<<<512, 256, 0, stream>>>(hx2, hy2, W2T2, b2, W3, out);
}

// Round 8
// 65.373 us; speedup vs baseline: 1.1839x; 1.0551x over previous
//
#include <hip/hip_runtime.h>
#include <hip/hip_fp16.h>

typedef __attribute__((ext_vector_type(8))) _Float16 half8;
typedef __attribute__((ext_vector_type(4))) float f32x4;

// DPP rotate-reduce within each 16-lane row: after ror 1,2,4,8 all 16 lanes
// hold the group sum. Validated numerically in R6/R7.
template <int CTRL>
__device__ __forceinline__ float dpp_ror_add(float p) {
  int s = __builtin_amdgcn_update_dpp(0, __float_as_int(p), CTRL, 0xF, 0xF, true);
  return p + __int_as_float(s);
}

__device__ __forceinline__ unsigned int pack_f16x2(float a, float b) {
  __half2 h = __floats2half2_rn(a, b);  // .x (low) = a
  return *reinterpret_cast<unsigned int*>(&h);
}

__device__ __forceinline__ half8 relu8(half8 s) {
  const _Float16 z = (_Float16)0.f;
#pragma unroll
  for (int e = 0; e < 8; ++e) s[e] = s[e] > z ? s[e] : z;
  return s;
}

// ---------------------------------------------------------------------------
// Precompute (fp32 math, f16 outputs, packed as uint pairs):
//   hx2[512][128] uint = f16 pairs of x @ W1[:128]
//   hy2[512][128] uint = f16 pairs of y @ W1[128:] + b1
//   W2T2[n][128]  uint = f16 pairs of W2[k][n] (transposed)
// grid 384 x 256 thr: b<64 hx | b<128 hy | b<384 W2T
// ---------------------------------------------------------------------------
__global__ void k_pre(const float* __restrict__ x, const float* __restrict__ y,
                      const float* __restrict__ W1, const float* __restrict__ b1,
                      const float* __restrict__ W2,
                      unsigned int* __restrict__ hx2, unsigned int* __restrict__ hy2,
                      unsigned int* __restrict__ W2T2) {
  const int b = blockIdx.x;
  const int t = threadIdx.x;
  if (b < 128) {
    const bool isx = (b < 64);
    const int i0 = (isx ? b : (b - 64)) * 8;
    const float* __restrict__ src = isx ? x : y;
    const float* __restrict__ W = W1 + (isx ? 0 : 128 * 256);
    float acc[8];
    const float binit = isx ? 0.0f : b1[t];
#pragma unroll
    for (int r = 0; r < 8; ++r) acc[r] = binit;
#pragma unroll 4
    for (int d = 0; d < 128; ++d) {
      const float wv = W[d * 256 + t];  // coalesced across t
#pragma unroll
      for (int r = 0; r < 8; ++r) acc[r] += src[(i0 + r) * 128 + d] * wv;  // uniform loads
    }
    unsigned int* __restrict__ dst = isx ? hx2 : hy2;
#pragma unroll
    for (int r = 0; r < 8; ++r) {
      const float o = __shfl_xor(acc[r], 1, 64);
      if (!(t & 1)) dst[(i0 + r) * 128 + (t >> 1)] = pack_f16x2(acc[r], o);
    }
  } else {
    const int n = b - 128;
    const float wv = W2[t * 256 + n];
    const float o = __shfl_xor(wv, 1, 64);
    if (!(t & 1)) W2T2[n * 128 + (t >> 1)] = pack_f16x2(wv, o);
  }
}

// ---------------------------------------------------------------------------
// Main fused kernel, v8: A never touches LDS; barrier-free main loop.
// Block = 512 thr (8 waves), grid = 512 (ig 0..63 x j-tile 0..7).
// Wave w = (rh = w>>2, cq = w&3): rows rh*32..+31 (mf=2), cols cq*64..+63 (nf=4).
// Persistent regs/wave: bq[8][4] half8 = 128 VGPR (W2T2 cols, B-frag layout),
//   hyf[2][8] half8 = 64 VGPR (hy rows in A-frag layout), acc 32 -> ~250 total.
// Per g (NO barrier): 8 kk x { broadcast ds_read hx(16B), af = relu8(hyf+hx)
//   in-register (A-frag layout!), 8 MFMA f16 } ; epilogue: relu(acc+b2).W3,
//   DPP 16-lane reduce, cndmask select, ONE 4B LDS write/lane into red.
// One __syncthreads total; final: 512 thr read 4 partials, store coalesced.
// MFMA f16 frag layout (verified R1/R7):
//   A: row=l15, k=8*l4+e ; B: col=l15, k=8*l4+e ; C: col=l15, row=4*l4+reg
// ---------------------------------------------------------------------------
__launch_bounds__(512, 2)
__global__ void k_main(const unsigned int* __restrict__ hx2,
                       const unsigned int* __restrict__ hy2,
                       const unsigned int* __restrict__ W2T2,
                       const float* __restrict__ b2, const float* __restrict__ W3,
                       const float* __restrict__ b3, float* __restrict__ out) {
  __shared__ __attribute__((aligned(16))) unsigned int hxL[8 * 128];  // 4 KB
  __shared__ float red[4 * 8 * 64];                                   // 8 KB

  const int tid = threadIdx.x;
  const int lane = tid & 63;
  const int w = tid >> 6;
  const int l15 = lane & 15;
  const int l4 = lane >> 4;
  const int rh = w >> 2;   // row-half: j-rows rh*32..+31
  const int cq = w & 3;    // col-quarter: n-cols cq*64..+63
  const int ig = blockIdx.x >> 3;
  const int j0 = (blockIdx.x & 7) * 64;
  const int i0 = ig * 8;

  // ---- stage hx rows i0..i0+7 into LDS (each thread 8B) ----
  *reinterpret_cast<uint2*>(&hxL[tid * 2]) =
      *reinterpret_cast<const uint2*>(&hx2[i0 * 128 + tid * 2]);

  // ---- persistent B fragments: col = cq*64+nf*16+l15, k = kk*32+l4*8 ----
  half8 bq[8][4];
  {
    const unsigned int* bb = W2T2 + (cq * 64 + l15) * 128 + l4 * 4;
#pragma unroll
    for (int nf = 0; nf < 4; ++nf)
#pragma unroll
      for (int kk = 0; kk < 8; ++kk)
        bq[kk][nf] = *reinterpret_cast<const half8*>(bb + nf * 16 * 128 + kk * 16);
  }

  // ---- persistent hy fragments (A-frag layout): row = rh*32+mf*16+l15 ----
  half8 hyf[2][8];
  {
    const unsigned int* hb = hy2 + (j0 + rh * 32 + l15) * 128 + l4 * 4;
#pragma unroll
    for (int mf = 0; mf < 2; ++mf)
#pragma unroll
      for (int kk = 0; kk < 8; ++kk)
        hyf[mf][kk] = *reinterpret_cast<const half8*>(hb + mf * 16 * 128 + kk * 16);
  }

  // ---- epilogue constants ----
  float b2v[4], w3v[4];
#pragma unroll
  for (int nf = 0; nf < 4; ++nf) {
    b2v[nf] = b2[cq * 64 + nf * 16 + l15];
    w3v[nf] = W3[cq * 64 + nf * 16 + l15];
  }
  const float b3v = b3[0];

  __syncthreads();  // hxL ready (only barrier before the final one)

#pragma unroll 1
  for (int g = 0; g < 8; ++g) {
    f32x4 acc[2][4];
#pragma unroll
    for (int mf = 0; mf < 2; ++mf)
#pragma unroll
      for (int nf = 0; nf < 4; ++nf) acc[mf][nf] = (f32x4){0.f, 0.f, 0.f, 0.f};

    const unsigned int* __restrict__ hxg = &hxL[g * 128];
#pragma unroll
    for (int kk = 0; kk < 8; ++kk) {
      const half8 hx8 = *reinterpret_cast<const half8*>(hxg + kk * 16 + l4 * 4);
      const half8 af0 = relu8(hyf[0][kk] + hx8);  // A-frag, in-register
      const half8 af1 = relu8(hyf[1][kk] + hx8);
      __builtin_amdgcn_s_setprio(1);
#pragma unroll
      for (int nf = 0; nf < 4; ++nf)
        acc[0][nf] = __builtin_amdgcn_mfma_f32_16x16x32_f16(af0, bq[kk][nf], acc[0][nf], 0, 0, 0);
#pragma unroll
      for (int nf = 0; nf < 4; ++nf)
        acc[1][nf] = __builtin_amdgcn_mfma_f32_16x16x32_f16(af1, bq[kk][nf], acc[1][nf], 0, 0, 0);
      __builtin_amdgcn_s_setprio(0);
    }

    // ---- epilogue: pr[mf][reg] = sum_nf relu(acc+b2)*w3 ----
    float pr[2][4];
#pragma unroll
    for (int mf = 0; mf < 2; ++mf)
#pragma unroll
      for (int reg = 0; reg < 4; ++reg) {
        float p = 0.f;
#pragma unroll
        for (int nf = 0; nf < 4; ++nf)
          p += fmaxf(acc[mf][nf][reg] + b2v[nf], 0.f) * w3v[nf];
        p = dpp_ror_add<0x121>(p);
        p = dpp_ror_add<0x122>(p);
        p = dpp_ror_add<0x124>(p);
        p = dpp_ror_add<0x128>(p);
        pr[mf][reg] = p;  // all 16 lanes of group hold the col-sum
      }

    // ---- select: lane takes pr[l15>>3][(l15>>1)&3] (2 lanes dup/row) ----
    const float q0 = (l15 & 2) ? pr[0][1] : pr[0][0];
    const float q1 = (l15 & 2) ? pr[0][3] : pr[0][2];
    const float q2 = (l15 & 2) ? pr[1][1] : pr[1][0];
    const float q3 = (l15 & 2) ? pr[1][3] : pr[1][2];
    const float r0 = (l15 & 4) ? q1 : q0;
    const float r1 = (l15 & 4) ? q3 : q2;
    const float v = (l15 & 8) ? r1 : r0;
    // row within 64: rh*32 + (l15>>3)*16 + l4*4 + ((l15>>1)&3)
    const int row64 = rh * 32 + (l15 >> 3) * 16 + l4 * 4 + ((l15 >> 1) & 3);
    red[(cq * 8 + g) * 64 + row64] = v;  // 2-way same-addr dup (free)
  }

  __syncthreads();  // all red written

  // ---- final: thread t -> (g = t>>6, j = t&63), sum 4 col-quarters ----
  {
    const int g = tid >> 6;
    const int j = tid & 63;
    const float s = red[(0 * 8 + g) * 64 + j] + red[(1 * 8 + g) * 64 + j] +
                    red[(2 * 8 + g) * 64 + j] + red[(3 * 8 + g) * 64 + j] + b3v;
    out[(i0 + g) * 512 + j0 + j] = s;
  }
}

extern "C" void kernel_launch(void* const* d_in, const int* in_sizes, int n_in,
                              void* d_out, int out_size, void* d_ws, size_t ws_size,
                              hipStream_t stream) {
  const float* x  = (const float*)d_in[0];
  const float* y  = (const float*)d_in[1];
  const float* W1 = (const float*)d_in[2];
  const float* b1 = (const float*)d_in[3];
  const float* W2 = (const float*)d_in[4];
  const float* b2 = (const float*)d_in[5];
  const float* W3 = (const float*)d_in[6];
  const float* b3 = (const float*)d_in[7];
  float* out = (float*)d_out;

  char* ws = (char*)d_ws;
  unsigned int* hx2  = (unsigned int*)ws;              // 512*128*4 = 262144 B
  unsigned int* hy2  = (unsigned int*)(ws + 262144);   // 262144 B
  unsigned int* W2T2 = (unsigned int*)(ws + 524288);   // 131072 B

  k_pre<<<384, 256, 0, stream>>>(x, y, W1, b1, W2, hx2, hy2, W2T2);
  k_main<<<512, 512, 0, stream>>>(hx2, hy2, W2T2, b2, W3, b3, out);
}